// Round 2
// baseline (509.377 us; speedup 1.0000x reference)
//
#include <hip/hip_runtime.h>
#include <hip/hip_bf16.h>

#define T_LEN 96
#define C_CH  66
#define FIN   7128   // 9*66*12
#define KPAD  7168   // 224*32
#define NFC1  1936
#define NPAD  2048
#define NCLS  14
#define SPLITK 2

typedef __bf16 bf16x8 __attribute__((ext_vector_type(8)));
typedef float  f32x4  __attribute__((ext_vector_type(4)));

#define GLD_LDS(gp, lp) __builtin_amdgcn_global_load_lds(                     \
    (__attribute__((address_space(1))) void*)(gp),                            \
    (__attribute__((address_space(3))) void*)(lp), 16, 0, 0)

// ---------------------------------------------------------------------------
// Kernel 1: w_fc1 (1936 x 7128 fp32) -> bf16 (2048 x 7168), zero padded.
__global__ __launch_bounds__(256) void pad_w_kernel(
    const float* __restrict__ w, __hip_bfloat16* __restrict__ wb)
{
    int idx = blockIdx.x * 256 + threadIdx.x;     // chunk id, total 2048*896
    int row = idx / 896;
    int cc  = idx - row * 896;                    // 896 chunks of 8 per row
    float4 a = {0.f, 0.f, 0.f, 0.f}, b = {0.f, 0.f, 0.f, 0.f};
    if (row < NFC1 && cc < 891) {                 // 891*8 = 7128
        const float4* src = (const float4*)(w + (size_t)row * FIN + cc * 8);
        a = src[0];
        b = src[1];
    }
    __align__(16) __hip_bfloat16 v[8];
    v[0] = __float2bfloat16(a.x); v[1] = __float2bfloat16(a.y);
    v[2] = __float2bfloat16(a.z); v[3] = __float2bfloat16(a.w);
    v[4] = __float2bfloat16(b.x); v[5] = __float2bfloat16(b.y);
    v[6] = __float2bfloat16(b.z); v[7] = __float2bfloat16(b.w);
    *(int4*)(wb + (size_t)row * KPAD + cc * 8) = *(const int4*)v;
}

// ---------------------------------------------------------------------------
// Kernel 2: feature extraction. One wave per (b,c) pair, 4 waves/block.
// Stage weights live in per-lane VGPRs (lane's oc fixed per stage); only
// activations round-trip LDS. Zero halos remove bounds checks; even tap
// bases let ds_read pairs merge to b64.
template <int K>
__device__ __forceinline__ void branch(
    int lane, const float* xbp, float* s1p, float* s2p,
    const float* __restrict__ wS, const float* __restrict__ bS,
    const float* __restrict__ wi1, const float* __restrict__ bi1,
    const float* __restrict__ wi2, const float* __restrict__ bi2,
    float* __restrict__ out)
{
    constexpr int PAD = K / 2;

    // stage 1: shared conv (1->8 ch, len 96) + relu + pool2 -> s1p[8][48]
    {
        const int oc = lane & 7;
        float wr[K];
        #pragma unroll
        for (int k = 0; k < K; k++) wr[k] = wS[oc * K + k];
        const float bv = bS[oc];
        #pragma unroll
        for (int it = 0; it < 6; it++) {
            const int p = (lane + it * 64) >> 3;   // low 3 bits stay = oc
            const float* xr = xbp + 2 * p + (3 - PAD);  // even base
            float y0 = bv, y1 = bv;
            #pragma unroll
            for (int k = 0; k < K; k++) {
                y0 = fmaf(wr[k], xr[k], y0);
                y1 = fmaf(wr[k], xr[k + 1], y1);
            }
            s1p[oc * 56 + 3 + p] = 0.5f * (fmaxf(y0, 0.f) + fmaxf(y1, 0.f));
        }
    }
    __syncthreads();

    // stage 2: grouped conv (8->4 ch, len 48) + relu + pool2 -> s2p[4][24]
    {
        const int oc = lane & 3;
        float wr[8 * K];
        #pragma unroll
        for (int j = 0; j < 8 * K; j++) wr[j] = wi1[oc * 8 * K + j];
        const float bv = bi1[oc];
        #pragma unroll
        for (int it = 0; it < 2; it++) {
            const int i = lane + it * 64;
            if (i < 96) {
                const int p = i >> 2;              // low 2 bits stay = oc
                float y0 = bv, y1 = bv;
                #pragma unroll
                for (int ic = 0; ic < 8; ic++) {
                    const float* sr = s1p + ic * 56 + 2 * p + (3 - PAD);
                    #pragma unroll
                    for (int k = 0; k < K; k++) {
                        y0 = fmaf(wr[ic * K + k], sr[k], y0);
                        y1 = fmaf(wr[ic * K + k], sr[k + 1], y1);
                    }
                }
                s2p[oc * 32 + 3 + p] = 0.5f * (fmaxf(y0, 0.f) + fmaxf(y1, 0.f));
            }
        }
    }
    __syncthreads();

    // stage 3: grouped conv (4->4 ch, len 24) + relu + pool2 -> out[4][12]
    if (lane < 48) {
        const int oc = lane & 3, p = lane >> 2;
        float y0 = bi2[oc], y1 = y0;
        #pragma unroll
        for (int ic = 0; ic < 4; ic++) {
            const float* sr = s2p + ic * 32 + 2 * p + (3 - PAD);
            #pragma unroll
            for (int k = 0; k < K; k++) {
                float w = wi2[(oc * 4 + ic) * K + k];
                y0 = fmaf(w, sr[k], y0);
                y1 = fmaf(w, sr[k + 1], y1);
            }
        }
        float r = 0.5f * (fmaxf(y0, 0.f) + fmaxf(y1, 0.f));
        ((__hip_bfloat16*)out)[oc * 12 + p] = __float2bfloat16(r);
    }
    __syncthreads();
}

__global__ __launch_bounds__(256) void feat_kernel(
    const float* __restrict__ x,
    const float* __restrict__ w_hs, const float* __restrict__ b_hs,
    const float* __restrict__ w_ls, const float* __restrict__ b_ls,
    const float* __restrict__ w_hi1, const float* __restrict__ b_hi1,
    const float* __restrict__ w_hi2, const float* __restrict__ b_hi2,
    const float* __restrict__ w_li1, const float* __restrict__ b_li1,
    const float* __restrict__ w_li2, const float* __restrict__ b_li2,
    __hip_bfloat16* __restrict__ feat)
{
    __shared__ __align__(16) float xbp_s[4][104];  // x + zero halos (idx = t+3)
    __shared__ __align__(16) float s1p_s[4][448];  // 8 rows, stride 56, halo 3
    __shared__ __align__(16) float s2p_s[4][128];  // 4 rows, stride 32, halo 3

    const int wid  = threadIdx.x >> 6;
    const int lane = threadIdx.x & 63;
    float* xbp = xbp_s[wid];
    float* s1p = s1p_s[wid];
    float* s2p = s2p_s[wid];

    const int pair = blockIdx.x * 4 + wid;         // exact grid: B*C/4 blocks
    const int b = pair / C_CH;
    const int c = pair - b * C_CH;

    // zero buffers (covers halos; interiors get overwritten)
    for (int i = lane; i < 104; i += 64) xbp[i] = 0.f;
    for (int i = lane; i < 448; i += 64) s1p[i] = 0.f;
    for (int i = lane; i < 128; i += 64) s2p[i] = 0.f;
    __syncthreads();

    for (int t = lane; t < T_LEN; t += 64)
        xbp[3 + t] = x[((size_t)b * T_LEN + t) * C_CH + c];
    __syncthreads();

    __hip_bfloat16* frow = feat + (size_t)b * KPAD + c * 108;

    // orig = pool2^3 = mean of 8 consecutive
    if (lane < 12) {
        float s = 0.f;
        #pragma unroll
        for (int k = 0; k < 8; k++) s += xbp[3 + lane * 8 + k];
        frow[lane] = __float2bfloat16(s * 0.125f);
    }
    // zero the K padding of this batch row once
    if (c == 0 && lane < (KPAD - FIN))
        feat[(size_t)b * KPAD + FIN + lane] = __float2bfloat16(0.f);

    branch<7>(lane, xbp, s1p, s2p, w_hs, b_hs,
              w_hi1 + c * 4 * 8 * 7, b_hi1 + c * 4,
              w_hi2 + c * 4 * 4 * 7, b_hi2 + c * 4,
              (float*)(frow + 60));                // high: j=5..8
    branch<3>(lane, xbp, s1p, s2p, w_ls, b_ls,
              w_li1 + c * 4 * 8 * 3, b_li1 + c * 4,
              w_li2 + c * 4 * 4 * 3, b_li2 + c * 4,
              (float*)(frow + 12));                // low: j=1..4
}

// ---------------------------------------------------------------------------
// Kernel 3: FC1 GEMM, A(2048xKPAD bf16) * W(2048xKPAD bf16)^T, split-K=2,
// plain fp32 stores into 2 slabs (no atomics); bias/relu/reduce in fc2.
__global__ __launch_bounds__(256) void gemm_kernel(
    const __hip_bfloat16* __restrict__ A,
    const __hip_bfloat16* __restrict__ Bw,
    float* __restrict__ Cm)
{
    __shared__ __align__(16) __hip_bfloat16 As[4096];  // 128 x 32
    __shared__ __align__(16) __hip_bfloat16 Bs[4096];  // 128 x 32

    const int tid  = threadIdx.x;
    const int lane = tid & 63;
    const int wid  = tid >> 6;
    const int m0 = blockIdx.y * 128;
    const int n0 = blockIdx.x * 128;
    const int wm = (wid >> 1) * 64;
    const int wn = (wid & 1) * 64;
    const int lr = lane & 15;
    const int quad = lane >> 4;

    // staging: chunk = tid; row = chunk>>2, col8 = (chunk&3)*8
    const int r0 = tid >> 2, c0 = (tid & 3) * 8;
    const __hip_bfloat16* gA0 = A  + (size_t)(m0 + r0) * KPAD + c0;
    const __hip_bfloat16* gA1 = gA0 + (size_t)64 * KPAD;
    const __hip_bfloat16* gB0 = Bw + (size_t)(n0 + r0) * KPAD + c0;
    const __hip_bfloat16* gB1 = gB0 + (size_t)64 * KPAD;
    __hip_bfloat16* lA0 = As + wid * 512;
    __hip_bfloat16* lA1 = As + 2048 + wid * 512;
    __hip_bfloat16* lB0 = Bs + wid * 512;
    __hip_bfloat16* lB1 = Bs + 2048 + wid * 512;

    f32x4 acc[4][4] = {};

    const int kBeg = blockIdx.z * (KPAD / SPLITK);
    const int kEnd = kBeg + (KPAD / SPLITK);
    for (int k0 = kBeg; k0 < kEnd; k0 += 32) {
        __syncthreads();
        GLD_LDS(gA0 + k0, lA0);
        GLD_LDS(gA1 + k0, lA1);
        GLD_LDS(gB0 + k0, lB0);
        GLD_LDS(gB1 + k0, lB1);
        __syncthreads();
        bf16x8 af[4], bfr[4];
        #pragma unroll
        for (int mt = 0; mt < 4; mt++)
            af[mt] = *(const bf16x8*)(As + (wm + mt * 16 + lr) * 32 + quad * 8);
        #pragma unroll
        for (int nt = 0; nt < 4; nt++)
            bfr[nt] = *(const bf16x8*)(Bs + (wn + nt * 16 + lr) * 32 + quad * 8);
        #pragma unroll
        for (int mt = 0; mt < 4; mt++)
            #pragma unroll
            for (int nt = 0; nt < 4; nt++)
                acc[mt][nt] = __builtin_amdgcn_mfma_f32_16x16x32_bf16(
                    af[mt], bfr[nt], acc[mt][nt], 0, 0, 0);
    }

    // epilogue: C/D layout col = lane&15, row = quad*4 + reg
    float* Cs = Cm + (size_t)blockIdx.z * NPAD * NPAD;
    #pragma unroll
    for (int mt = 0; mt < 4; mt++) {
        #pragma unroll
        for (int nt = 0; nt < 4; nt++) {
            const int col = n0 + wn + nt * 16 + lr;
            const int rb  = m0 + wm + mt * 16 + quad * 4;
            #pragma unroll
            for (int r = 0; r < 4; r++)
                Cs[(size_t)(rb + r) * NPAD + col] = acc[mt][nt][r];
        }
    }
}

// ---------------------------------------------------------------------------
// Kernel 4: reduce split-K slabs + bias + relu, then FC2. One block per row.
__global__ __launch_bounds__(256) void fc2_kernel(
    const float* __restrict__ h1, const float* __restrict__ b1,
    const float* __restrict__ w2, const float* __restrict__ b2,
    float* __restrict__ out)
{
    const int b = blockIdx.x;
    const int tid = threadIdx.x;
    float acc[NCLS];
    #pragma unroll
    for (int o = 0; o < NCLS; o++) acc[o] = 0.f;
    const float* h0r = h1 + (size_t)b * NPAD;
    const float* h1r = h0r + (size_t)NPAD * NPAD;
    for (int n = tid; n < NFC1; n += 256) {
        float h = fmaxf(h0r[n] + h1r[n] + b1[n], 0.f);
        #pragma unroll
        for (int o = 0; o < NCLS; o++)
            acc[o] = fmaf(h, w2[o * NFC1 + n], acc[o]);
    }
    __shared__ float red[4][NCLS];
    #pragma unroll
    for (int o = 0; o < NCLS; o++) {
        float v = acc[o];
        #pragma unroll
        for (int s = 32; s > 0; s >>= 1) v += __shfl_down(v, s);
        if ((tid & 63) == 0) red[tid >> 6][o] = v;
    }
    __syncthreads();
    if (tid < NCLS)
        out[b * NCLS + tid] = red[0][tid] + red[1][tid] + red[2][tid] +
                              red[3][tid] + b2[tid];
}

// ---------------------------------------------------------------------------
extern "C" void kernel_launch(void* const* d_in, const int* in_sizes, int n_in,
                              void* d_out, int out_size, void* d_ws, size_t ws_size,
                              hipStream_t stream)
{
    (void)n_in; (void)out_size; (void)ws_size;
    const float* x     = (const float*)d_in[0];
    const float* w_hs  = (const float*)d_in[1];
    const float* b_hs  = (const float*)d_in[2];
    const float* w_ls  = (const float*)d_in[3];
    const float* b_ls  = (const float*)d_in[4];
    const float* w_hi1 = (const float*)d_in[5];
    const float* b_hi1 = (const float*)d_in[6];
    const float* w_hi2 = (const float*)d_in[7];
    const float* b_hi2 = (const float*)d_in[8];
    const float* w_li1 = (const float*)d_in[9];
    const float* b_li1 = (const float*)d_in[10];
    const float* w_li2 = (const float*)d_in[11];
    const float* b_li2 = (const float*)d_in[12];
    const float* w_fc1 = (const float*)d_in[13];
    const float* b_fc1 = (const float*)d_in[14];
    const float* w_fc2 = (const float*)d_in[15];
    const float* b_fc2 = (const float*)d_in[16];
    float* out = (float*)d_out;

    const int B = in_sizes[0] / (T_LEN * C_CH);    // 2048

    char* ws = (char*)d_ws;
    __hip_bfloat16* feat = (__hip_bfloat16*)ws;                 // B*KPAD*2
    __hip_bfloat16* wb = (__hip_bfloat16*)(ws + (size_t)B * KPAD * 2);
    float* h1 = (float*)(ws + (size_t)B * KPAD * 2 + (size_t)NPAD * KPAD * 2);
    // total ws use: 28 MiB + 28 MiB + 32 MiB = 88 MiB

    pad_w_kernel<<<dim3((NPAD * 896) / 256), 256, 0, stream>>>(w_fc1, wb);
    feat_kernel<<<dim3((B * C_CH) / 4), 256, 0, stream>>>(
        x, w_hs, b_hs, w_ls, b_ls, w_hi1, b_hi1, w_hi2, b_hi2,
        w_li1, b_li1, w_li2, b_li2, feat);
    gemm_kernel<<<dim3(NPAD / 128, B / 128, SPLITK), 256, 0, stream>>>(feat, wb, h1);
    fc2_kernel<<<dim3(B), 256, 0, stream>>>(h1, b_fc1, w_fc2, b_fc2, out);
}